// Round 5
// baseline (790.839 us; speedup 1.0000x reference)
//
#include <hip/hip_runtime.h>
#include <hip/hip_bf16.h>
#include <math.h>

// Problem constants (fixed shapes from setup_inputs)
#define NB 8
#define CI 256
#define CD 128
#define HH 128
#define WW 128
#define HW (HH*WW)          // 16384
#define AANG 180
#define RRHO 180
#define PADD 182            // 180 + 2 (zero pad for 3x3 convs)
#define M2 (AANG*RRHO)      // 32400 output pixels per image for conv2/3

typedef __attribute__((ext_vector_type(8))) short short8;
typedef __attribute__((ext_vector_type(8))) _Float16 half8;
typedef __attribute__((ext_vector_type(2))) _Float16 h2;
typedef __attribute__((ext_vector_type(4))) float floatx4;
typedef __attribute__((ext_vector_type(2))) float floatx2;

static __device__ __forceinline__ void async_cp16(const void* g, void* l) {
  __builtin_amdgcn_global_load_lds((const __attribute__((address_space(1))) unsigned int*)g,
                                   (__attribute__((address_space(3))) unsigned int*)l,
                                   16, 0, 0);
}

static __device__ __forceinline__ unsigned short f2bf(float f) {
  unsigned int u = __builtin_bit_cast(unsigned int, f);
  unsigned int r = (u + 0x7fffu + ((u >> 16) & 1u)) >> 16;
  return (unsigned short)r;
}

static __device__ __forceinline__ unsigned short f2h(float f) {
  return __builtin_bit_cast(unsigned short, (_Float16)f);
}

// Accumulate both f16 halves of u into separate f32 accumulators.
// v_dot2_f32_f16 with basis vectors: 1 VALU op per channel-add, no unpack.
static __device__ __forceinline__ void acc2(float& aL, float& aH, unsigned int u,
                                            h2 eL, h2 eH) {
  h2 hv = __builtin_bit_cast(h2, u);
#if __has_builtin(__builtin_amdgcn_fdot2)
  aL = __builtin_amdgcn_fdot2(hv, eL, aL, false);
  aH = __builtin_amdgcn_fdot2(hv, eH, aH, false);
#else
  aL += (float)hv.x;
  aH += (float)hv.y;
#endif
}

static __device__ __forceinline__ void acc4(float* aL, float* aH, const uint4& v,
                                            h2 eL, h2 eH) {
  acc2(aL[0], aH[0], v.x, eL, eH);
  acc2(aL[1], aH[1], v.y, eL, eH);
  acc2(aL[2], aH[2], v.z, eL, eH);
  acc2(aL[3], aH[3], v.w, eL, eH);
}

// ---------------------------------------------------------------------------
// prep: weight repack + BN scale/shift folding.
// wK1 fp16 [co][ci] (conv1 f16 MFMA).
// wK2/wK3 bf16 repacked STEP-MAJOR for coalesced conv staging:
//   [step = dydx*2 + (ci>>6)][co 0..127][ci&63]  -> each 16 KB tile contiguous.
// ---------------------------------------------------------------------------
__global__ void prep_kernel(const float* __restrict__ w1, const float* __restrict__ w2,
                            const float* __restrict__ w3,
                            const float* b1, const float* g1, const float* be1,
                            const float* m1, const float* v1,
                            const float* b2, const float* g2, const float* be2,
                            const float* m2, const float* v2,
                            const float* b3, const float* g3, const float* be3,
                            const float* m3, const float* v3,
                            unsigned short* __restrict__ wK1, unsigned short* __restrict__ wK2,
                            unsigned short* __restrict__ wK3,
                            float* __restrict__ sc, float* __restrict__ sh) {
  int idx = blockIdx.x * 256 + threadIdx.x;
  if (idx < 32768) {
    wK1[idx] = f2h(w1[idx]);                       // w1 is already [co][ci]
  } else if (idx < 32768 + 147456) {
    int i = idx - 32768;
    int co = i / 1152, k = i % 1152;
    int dydx = k >> 7, ci = k & 127;
    int dst = (((dydx*2 + (ci >> 6)) * 128 + co) * 64) + (ci & 63);
    wK2[dst] = f2bf(w2[(size_t)(co*128 + ci)*9 + dydx]);
  } else if (idx < 32768 + 2*147456) {
    int i = idx - 32768 - 147456;
    int co = i / 1152, k = i % 1152;
    int dydx = k >> 7, ci = k & 127;
    int dst = (((dydx*2 + (ci >> 6)) * 128 + co) * 64) + (ci & 63);
    wK3[dst] = f2bf(w3[(size_t)(co*128 + ci)*9 + dydx]);
  } else if (idx < 32768 + 2*147456 + 384) {
    int j = idx - 32768 - 2*147456;
    int c = j >> 7, co = j & 127;
    const float* b  = c==0?b1 :(c==1?b2 :b3);
    const float* g  = c==0?g1 :(c==1?g2 :g3);
    const float* be = c==0?be1:(c==1?be2:be3);
    const float* m  = c==0?m1 :(c==1?m2 :m3);
    const float* v  = c==0?v1 :(c==1?v2 :v3);
    float s = g[co] * rsqrtf(v[co] + 1e-5f);
    sc[c*128 + co] = s;
    sh[c*128 + co] = (b[co] - m[co]) * s + be[co];
  }
}

// ---------------------------------------------------------------------------
// Hough binning tables. fp64 to exactly match numpy (round-half-even via rint).
// irho = int(sqrt(128^2+128^2)+1)/(180-1) = 182/179
// ---------------------------------------------------------------------------
__global__ void hist_kernel(unsigned char* __restrict__ seg, unsigned int* __restrict__ offs) {
  int a = blockIdx.x, t = threadIdx.x;
  __shared__ unsigned int h[RRHO];
  if (t < RRHO) h[t] = 0;
  __syncthreads();
  double th = (double)a * (M_PI / 180.0);
  double Cc = cos(th) / (182.0 / 179.0);
  double Ss = sin(th) / (182.0 / 179.0);
  for (int p = t; p < HW; p += 256) {
    int x = (p & 127) - 64;   // width index
    int y = (p >> 7) - 64;    // height index
    int r = (int)rint(Cc * (double)x + Ss * (double)y) + 90;
    r = r < 0 ? 0 : (r > 179 ? 179 : r);
    seg[(size_t)a*HW + p] = (unsigned char)r;
    atomicAdd(&h[r], 1u);
  }
  __syncthreads();
  if (t == 0) {
    unsigned int run = 0;
    for (int r = 0; r < RRHO; ++r) { offs[a*192 + r] = run; run += h[r]; }
    offs[a*192 + RRHO] = run;
  }
}

// Pixel lists packed as ushort (p < 16384 fits) -> 32 KB per angle.
// Each thread owns a CONTIGUOUS 64-px raster range so every bin's list is a
// concatenation of few raster-sorted runs (address locality for the gather).
__global__ void fill_kernel(const unsigned char* __restrict__ seg,
                            const unsigned int* __restrict__ offs,
                            unsigned short* __restrict__ lst16) {
  int a = blockIdx.x, t = threadIdx.x;
  __shared__ unsigned int pos[RRHO];
  if (t < RRHO) pos[t] = offs[a*192 + t];
  __syncthreads();
  int p0 = t * 64;
  for (int i = 0; i < 64; ++i) {
    int p = p0 + i;
    int r = seg[(size_t)a*HW + p];
    unsigned int ix = atomicAdd(&pos[r], 1u);
    lst16[(size_t)a*HW + ix] = (unsigned short)p;
  }
}

// Zero the 1-px borders of the two padded activation buffers (ws is poisoned),
// plus the 8 DHT work-queue counters.
__global__ void zero_border(uint4* __restrict__ accP, uint4* __restrict__ y2P,
                            unsigned int* __restrict__ qcnt) {
  int idx = blockIdx.x * 256 + threadIdx.x;
  if (idx < 8) qcnt[idx] = 0;
  if (idx >= NB * PADD * PADD) return;
  int rc = idx % (PADD * PADD);
  int row = rc / PADD, col = rc % PADD;
  if (row != 0 && row != PADD-1 && col != 0 && col != PADD-1) return;
  uint4 z = {0u, 0u, 0u, 0u};
  size_t base = (size_t)idx * 16;  // 128 bf16 = 16 uint4 per cell
  #pragma unroll
  for (int i = 0; i < 16; ++i) { accP[base + i] = z; y2P[base + i] = z; }
}

// ---------------------------------------------------------------------------
// conv1: 1x1 conv as MFMA GEMM (f16). A = x (fp32 -> f16 via cvt_pkrtz in
// staging), B = wK1 f16 (global_load_lds). Output f[n][pixel][co] f16
// channels-last.
// ---------------------------------------------------------------------------
__global__ __launch_bounds__(256) void conv1_kernel(
    const float* __restrict__ x, const unsigned short* __restrict__ wK,
    const float* __restrict__ sc, const float* __restrict__ sh,
    unsigned short* __restrict__ f) {
  __shared__ short Al[4*128*8];
  __shared__ short Bl[4*128*8];
  int t = threadIdx.x;
  int m0 = blockIdx.x * 128;
  int n = blockIdx.y;
  int lane = t & 63, wv = t >> 6, wm = wv & 1, wn = wv >> 1;
  int mloc = t & 127, octb = t >> 7;
  floatx4 acc[4][4];
  #pragma unroll
  for (int i = 0; i < 4; ++i)
    #pragma unroll
    for (int j = 0; j < 4; ++j) acc[i][j] = (floatx4){0.f, 0.f, 0.f, 0.f};
  const float* xn = x + (size_t)n * CI * HW;
  for (int kc = 0; kc < 8; ++kc) {
    if (kc) __syncthreads();
    // A: load 8 k-strided fp32 per pass, pack to f16 pairs, store [oct][m][8]
    #pragma unroll
    for (int j = 0; j < 2; ++j) {
      int oct = octb + 2*j;
      const float* src = xn + (size_t)(kc*32 + oct*8) * HW + m0 + mloc;
      float v[8];
      #pragma unroll
      for (int e = 0; e < 8; ++e) v[e] = src[(size_t)e * HW];
      uint4 pk;
      pk.x = __builtin_bit_cast(unsigned int, __builtin_amdgcn_cvt_pkrtz(v[0], v[1]));
      pk.y = __builtin_bit_cast(unsigned int, __builtin_amdgcn_cvt_pkrtz(v[2], v[3]));
      pk.z = __builtin_bit_cast(unsigned int, __builtin_amdgcn_cvt_pkrtz(v[4], v[5]));
      pk.w = __builtin_bit_cast(unsigned int, __builtin_amdgcn_cvt_pkrtz(v[6], v[7]));
      *reinterpret_cast<uint4*>(&Al[(size_t)(t + 256*j) * 8]) = pk;
    }
    // B: async 16B direct-to-LDS
    #pragma unroll
    for (int j = 0; j < 2; ++j) {
      int oct = octb + 2*j;
      async_cp16(wK + (size_t)mloc * 256 + kc*32 + oct*8,
                 &Bl[(size_t)((t & 0xFFC0) + 256*j) * 8]);
    }
    __syncthreads();
    int q = lane >> 4, l15 = lane & 15;
    short8 af[4], bfr[4];
    #pragma unroll
    for (int i = 0; i < 4; ++i)
      af[i] = *reinterpret_cast<const short8*>(&Al[((q*128) + wm*64 + i*16 + l15) * 8]);
    #pragma unroll
    for (int j = 0; j < 4; ++j)
      bfr[j] = *reinterpret_cast<const short8*>(&Bl[((q*128) + wn*64 + j*16 + l15) * 8]);
    #pragma unroll
    for (int i = 0; i < 4; ++i)
      #pragma unroll
      for (int j = 0; j < 4; ++j)
        acc[i][j] = __builtin_amdgcn_mfma_f32_16x16x32_f16(
            __builtin_bit_cast(half8, af[i]), __builtin_bit_cast(half8, bfr[j]),
            acc[i][j], 0, 0, 0);
  }
  int q = lane >> 4, l15 = lane & 15;
  #pragma unroll
  for (int j = 0; j < 4; ++j) {
    int co = wn*64 + j*16 + l15;
    float s = sc[co], hb = sh[co];
    #pragma unroll
    for (int i = 0; i < 4; ++i) {
      #pragma unroll
      for (int rg = 0; rg < 4; ++rg) {
        int m = m0 + wm*64 + i*16 + q*4 + rg;
        float v = acc[i][j][rg] * s + hb;
        v = fmaxf(v, 0.f);
        f[((size_t)n * HW + m) * 128 + co] = f2h(v);
      }
    }
  }
}

// ---------------------------------------------------------------------------
// DHT gather v8: front/back dual-stream within each bin. The main loop walks
// the bin's pixel list from BOTH ends into the SAME accumulators (addition
// commutes): 8 independent dwordx4 gathers in flight per wave (~6.3 MB
// chip-wide > 2x the L2 BDP) with ZERO extra accumulator state -- v7's
// dual-bin spill (+80 MB scratch) came from duplicating acc, not the loads.
// 512 thr / 8 waves / 33.5 KB LDS -> 4 blocks x 8 waves = 32 waves/CU.
// Per-XCD work queues via HW_REG_XCC_ID keep each image-half in its L2.
// ---------------------------------------------------------------------------
__global__ __launch_bounds__(512, 8) void dht_kernel(
    const unsigned short* __restrict__ lst16, const unsigned int* __restrict__ offs,
    const unsigned int* __restrict__ f, unsigned int* __restrict__ accP,
    unsigned int* __restrict__ qcnt) {
  __shared__ unsigned short Ls[HW];     // 32 KB pixel list for this angle
  __shared__ unsigned int Os[RRHO + 1];
  __shared__ int sWork;
  int t = threadIdx.x;
  if (t == 0) {
    unsigned int xcd;
    asm volatile("s_getreg_b32 %0, hwreg(HW_REG_XCC_ID, 0, 32)" : "=s"(xcd));
    xcd &= 7u;
    int work = 0;
    for (int k = 0; k < 8; ++k) {
      unsigned int q = (xcd + (unsigned int)k) & 7u;
      unsigned int tk = atomicAdd(&qcnt[q], 1u);
      if (tk < 360u) { work = (int)(q * 360u + tk); break; }
    }
    sWork = work;
  }
  __syncthreads();
  int work = sWork;
  int n = work / 360;          // image == (ideally) this XCD
  int rem = work % 360;
  int h = rem / 180;           // channel half; co-resident tickets share h
  int a = rem % 180;
  // Stage list + offsets into LDS (sequential uint4 reads, fully coalesced).
  {
    const uint4* src = (const uint4*)(lst16 + (size_t)a * HW);  // 2048 uint4
    uint4* dst = (uint4*)Ls;
    if (t < RRHO + 1) Os[t] = offs[a*192 + t];
    #pragma unroll
    for (int i = 0; i < 4; ++i) dst[t + 512*i] = src[t + 512*i];
  }
  __syncthreads();
  int w = t >> 6, lane = t & 63;
  int sub = lane >> 3;         // which of 8 pixels in the load group
  int co  = lane & 7;          // channel octet within the half
  // Wave-uniform byte base; per-lane 32-bit offset -> saddr-form dwordx4.
  const char* fb = (const char*)(f + (size_t)n * HW * 64);
  unsigned int loff = (unsigned int)(h*32 + co*4) * 4u;
  const h2 eL = {(_Float16)1.0f, (_Float16)0.0f};
  const h2 eH = {(_Float16)0.0f, (_Float16)1.0f};
  for (int r = w; r < RRHO; r += 8) {
    int lo = (int)Os[r];
    int hi = (int)Os[r+1];
    float accL[4], accH[4];
    #pragma unroll
    for (int j = 0; j < 4; ++j) { accL[j] = 0.f; accH[j] = 0.f; }
    // Dual-stream main loop: 8 loads in flight, one accumulator set.
    while (hi - lo >= 64) {
      unsigned int p0 = Ls[lo + sub];
      unsigned int p1 = Ls[lo + 8 + sub];
      unsigned int p2 = Ls[lo + 16 + sub];
      unsigned int p3 = Ls[lo + 24 + sub];
      unsigned int p4 = Ls[hi - 32 + sub];
      unsigned int p5 = Ls[hi - 24 + sub];
      unsigned int p6 = Ls[hi - 16 + sub];
      unsigned int p7 = Ls[hi - 8 + sub];
      uint4 v0 = *(const uint4*)(fb + ((p0 << 8) + loff));
      uint4 v1 = *(const uint4*)(fb + ((p1 << 8) + loff));
      uint4 v2 = *(const uint4*)(fb + ((p2 << 8) + loff));
      uint4 v3 = *(const uint4*)(fb + ((p3 << 8) + loff));
      uint4 v4 = *(const uint4*)(fb + ((p4 << 8) + loff));
      uint4 v5 = *(const uint4*)(fb + ((p5 << 8) + loff));
      uint4 v6 = *(const uint4*)(fb + ((p6 << 8) + loff));
      uint4 v7 = *(const uint4*)(fb + ((p7 << 8) + loff));
      acc4(accL, accH, v0, eL, eH); acc4(accL, accH, v1, eL, eH);
      acc4(accL, accH, v2, eL, eH); acc4(accL, accH, v3, eL, eH);
      acc4(accL, accH, v4, eL, eH); acc4(accL, accH, v5, eL, eH);
      acc4(accL, accH, v6, eL, eH); acc4(accL, accH, v7, eL, eH);
      lo += 32; hi -= 32;
    }
    // Remaining [lo, hi): fewer than 64 pixels.
    for (; lo + 32 <= hi; lo += 32) {
      unsigned int p0 = Ls[lo + sub];
      unsigned int p1 = Ls[lo + 8 + sub];
      unsigned int p2 = Ls[lo + 16 + sub];
      unsigned int p3 = Ls[lo + 24 + sub];
      uint4 v0 = *(const uint4*)(fb + ((p0 << 8) + loff));
      uint4 v1 = *(const uint4*)(fb + ((p1 << 8) + loff));
      uint4 v2 = *(const uint4*)(fb + ((p2 << 8) + loff));
      uint4 v3 = *(const uint4*)(fb + ((p3 << 8) + loff));
      acc4(accL, accH, v0, eL, eH); acc4(accL, accH, v1, eL, eH);
      acc4(accL, accH, v2, eL, eH); acc4(accL, accH, v3, eL, eH);
    }
    for (; lo + 8 <= hi; lo += 8) {
      unsigned int p0 = Ls[lo + sub];
      uint4 v0 = *(const uint4*)(fb + ((p0 << 8) + loff));
      acc4(accL, accH, v0, eL, eH);
    }
    if (lo < hi) {
      int idx = lo + sub;
      int cl = idx < hi ? idx : (hi - 1);
      unsigned int p0 = Ls[cl];
      uint4 v0 = *(const uint4*)(fb + ((p0 << 8) + loff));
      if (idx >= hi) { v0.x = 0; v0.y = 0; v0.z = 0; v0.w = 0; }
      acc4(accL, accH, v0, eL, eH);
    }
    // Butterfly reduce across the 8 pixel-subgroups (lane bits 3,4,5).
    #pragma unroll
    for (int m = 8; m <= 32; m <<= 1) {
      #pragma unroll
      for (int j = 0; j < 4; ++j) {
        accL[j] += __shfl_xor(accL[j], m, 64);
        accH[j] += __shfl_xor(accH[j], m, 64);
      }
    }
    if (sub == 0) {
      uint4 out;
      out.x = (unsigned int)f2bf(accL[0]) | ((unsigned int)f2bf(accH[0]) << 16);
      out.y = (unsigned int)f2bf(accL[1]) | ((unsigned int)f2bf(accH[1]) << 16);
      out.z = (unsigned int)f2bf(accL[2]) | ((unsigned int)f2bf(accH[2]) << 16);
      out.w = (unsigned int)f2bf(accL[3]) | ((unsigned int)f2bf(accH[3]) << 16);
      size_t o = (((size_t)n*PADD + (a+1))*PADD + (r+1))*64 + h*32 + co*4;
      *(uint4*)(accP + o) = out;
    }
  }
}

// ---------------------------------------------------------------------------
// 3x3 conv v3: implicit GEMM, BK=64, DOUBLE-BUFFERED LDS (2-phase pipeline,
// T3/T4 minimum form). stage(step+1 -> buf^1) is issued BEFORE compute(step);
// the mid barrier uses counted "s_waitcnt vmcnt(8)" (current tile's 8 loads
// retired, next tile's 8 stay in flight -- never drain to 0 mid-loop), and
// the end barrier waits lgkmcnt(0) only. This hides the per-step L2 staging
// latency under the 32 MFMAs that previously ran back-to-back with a full
// vmcnt(0) drain between every stage+compute (single-buffer __syncthreads).
// LDS 64 KB -> 2 blocks/CU. Staging stays line-coalesced (step-major weights,
// 8 rows x 128 B per wave-op) with the mod-8 octet rotation swizzle.
// MODE 1: conv2 -> bf16 padded channels-last out. MODE 2: conv3 -> fp32 NCHW,
// operands swapped so stores are contiguous along rho.
// ---------------------------------------------------------------------------
template<int MODE>
__global__ __launch_bounds__(256) void conv3x3_kernel(
    const unsigned short* __restrict__ inP,   // [N][182][182][128] bf16
    const unsigned short* __restrict__ wKr,   // [18][128][64] bf16 step-major
    const float* __restrict__ sc, const float* __restrict__ sh,
    void* __restrict__ outp) {
  __shared__ short Al[2][128*64];   // 2 x 16 KB
  __shared__ short Bl[2][128*64];   // 2 x 16 KB
  int t = threadIdx.x;
  int m0 = blockIdx.x * 128;
  int n = blockIdx.y;
  int lane = t & 63, w = t >> 6, wm = w & 1, wn = w >> 1;
  floatx4 acc[4][4];
  #pragma unroll
  for (int i = 0; i < 4; ++i)
    #pragma unroll
    for (int j = 0; j < 4; ++j) acc[i][j] = (floatx4){0.f, 0.f, 0.f, 0.f};

  // Staging geometry: 1024 slots of 16 B; slot s = (w*4+i)*64 + lane;
  // row = s>>3, oct slot p = s&7. Source octet = (p - row) & 7 == the
  // per-thread constant below (same for all i).
  int srcOct = ((lane & 7) - (lane >> 3)) & 7;
  const unsigned short* rpA[4];
  unsigned int offB[4];
  #pragma unroll
  for (int i = 0; i < 4; ++i) {
    int row = w*32 + i*8 + (lane >> 3);
    int mg = m0 + row; if (mg > M2 - 1) mg = M2 - 1;
    int oa = mg / 180, orr = mg % 180;
    rpA[i] = inP + (((size_t)n*PADD + oa)*PADD + orr)*128 + srcOct*8;
    offB[i] = (unsigned int)(row*64 + srcOct*8);
  }

  auto stage = [&](int step, int b) {
    int dydx = step >> 1, cc2 = step & 1;
    int dy = (dydx * 11) >> 5, dx = dydx - dy*3;
    int doff = (dy*PADD + dx)*128 + cc2*64;
    #pragma unroll
    for (int i = 0; i < 4; ++i) {
      async_cp16(rpA[i] + doff, &Al[b][(size_t)((w*4 + i)*64 + lane) * 8]);
      async_cp16(wKr + (size_t)step*8192 + offB[i],
                 &Bl[b][(size_t)((w*4 + i)*64 + lane) * 8]);
    }
  };
  auto compute = [&](int b) {
    int q = lane >> 4, l15 = lane & 15;
    #pragma unroll
    for (int kk = 0; kk < 2; ++kk) {
      int o = kk*4 + q;
      int swz = ((o + l15) & 7) * 8;
      short8 rf[4], cf[4];
      #pragma unroll
      for (int i = 0; i < 4; ++i) {
        int addr = (wm*64 + i*16 + l15)*64 + swz;
        rf[i] = *reinterpret_cast<const short8*>(MODE == 1 ? &Al[b][addr] : &Bl[b][addr]);
      }
      #pragma unroll
      for (int j = 0; j < 4; ++j) {
        int addr = (wn*64 + j*16 + l15)*64 + swz;
        cf[j] = *reinterpret_cast<const short8*>(MODE == 1 ? &Bl[b][addr] : &Al[b][addr]);
      }
      #pragma unroll
      for (int i = 0; i < 4; ++i)
        #pragma unroll
        for (int j = 0; j < 4; ++j)
          acc[i][j] = __builtin_amdgcn_mfma_f32_16x16x32_bf16(rf[i], cf[j], acc[i][j], 0, 0, 0);
    }
  };

  stage(0, 0);
  #pragma unroll 1
  for (int s2 = 0; s2 < 9; ++s2) {
    // Even phase: stage odd step into buf1, compute even step from buf0.
    stage(2*s2 + 1, 1);
    asm volatile("s_waitcnt vmcnt(8)" ::: "memory");
    __builtin_amdgcn_s_barrier();
    __builtin_amdgcn_sched_barrier(0);
    compute(0);
    asm volatile("s_waitcnt lgkmcnt(0)" ::: "memory");
    __builtin_amdgcn_s_barrier();
    // Odd phase: stage next even step into buf0, compute odd step from buf1.
    if (s2 < 8) {
      stage(2*s2 + 2, 0);
      asm volatile("s_waitcnt vmcnt(8)" ::: "memory");
    } else {
      asm volatile("s_waitcnt vmcnt(0)" ::: "memory");
    }
    __builtin_amdgcn_s_barrier();
    __builtin_amdgcn_sched_barrier(0);
    compute(1);
    asm volatile("s_waitcnt lgkmcnt(0)" ::: "memory");
    __builtin_amdgcn_s_barrier();
  }

  int q = lane >> 4, l15 = lane & 15;
  if (MODE == 1) {
    unsigned short* out = (unsigned short*)outp;
    #pragma unroll
    for (int j = 0; j < 4; ++j) {
      int co = wn*64 + j*16 + l15;
      float s = sc[co], hb = sh[co];
      #pragma unroll
      for (int i = 0; i < 4; ++i) {
        #pragma unroll
        for (int rg = 0; rg < 4; ++rg) {
          int m = m0 + wm*64 + i*16 + q*4 + rg;
          if (m < M2) {
            float v = fmaxf(acc[i][j][rg] * s + hb, 0.f);
            int oa2 = m / 180, or2 = m % 180;
            out[(((size_t)n*PADD + oa2 + 1)*PADD + or2 + 1)*128 + co] = f2bf(v);
          }
        }
      }
    }
  } else {
    float* out = (float*)outp;
    #pragma unroll
    for (int i = 0; i < 4; ++i) {
      #pragma unroll
      for (int rg = 0; rg < 4; ++rg) {
        int co = wm*64 + i*16 + q*4 + rg;
        float s = sc[co], hb = sh[co];
        #pragma unroll
        for (int j = 0; j < 4; ++j) {
          int m = m0 + wn*64 + j*16 + l15;
          if (m < M2) {
            float v = fmaxf(acc[i][j][rg] * s + hb, 0.f);
            out[((size_t)n*128 + co)*M2 + m] = v;
          }
        }
      }
    }
  }
}

// ---------------------------------------------------------------------------
extern "C" void kernel_launch(void* const* d_in, const int* in_sizes, int n_in,
                              void* d_out, int out_size, void* d_ws, size_t ws_size,
                              hipStream_t stream) {
  const float* x  = (const float*)d_in[0];
  const float* w1 = (const float*)d_in[1];
  const float* b1 = (const float*)d_in[2];
  const float* g1 = (const float*)d_in[3];
  const float* be1= (const float*)d_in[4];
  const float* m1 = (const float*)d_in[5];
  const float* v1 = (const float*)d_in[6];
  const float* w2 = (const float*)d_in[7];
  const float* b2 = (const float*)d_in[8];
  const float* g2 = (const float*)d_in[9];
  const float* be2= (const float*)d_in[10];
  const float* m2 = (const float*)d_in[11];
  const float* v2 = (const float*)d_in[12];
  const float* w3 = (const float*)d_in[13];
  const float* b3 = (const float*)d_in[14];
  const float* g3 = (const float*)d_in[15];
  const float* be3= (const float*)d_in[16];
  const float* m3 = (const float*)d_in[17];
  const float* v3 = (const float*)d_in[18];

  size_t off = 0;
  char* ws = (char*)d_ws;
  auto alloc = [&](size_t sz) -> void* {
    void* p = ws + off;
    off = (off + sz + 255) & ~(size_t)255;
    return p;
  };
  unsigned short* fbuf = (unsigned short*)alloc((size_t)NB*HW*128*2);        // 33.6 MB
  unsigned short* accP = (unsigned short*)alloc((size_t)NB*PADD*PADD*128*2); // 67.8 MB
  unsigned short* y2P  = (unsigned short*)alloc((size_t)NB*PADD*PADD*128*2); // 67.8 MB
  unsigned short* wK1  = (unsigned short*)alloc(32768*2);
  unsigned short* wK2  = (unsigned short*)alloc(147456*2);
  unsigned short* wK3  = (unsigned short*)alloc(147456*2);
  float* sc = (float*)alloc(384*4);
  float* sh = (float*)alloc(384*4);
  unsigned char* seg  = (unsigned char*)alloc((size_t)AANG*HW);
  unsigned int* offs  = (unsigned int*)alloc((size_t)AANG*192*4);
  unsigned short* lst16 = (unsigned short*)alloc((size_t)AANG*HW*2);
  unsigned int* qcnt  = (unsigned int*)alloc(8*4);

  prep_kernel<<<1282, 256, 0, stream>>>(w1, w2, w3,
      b1, g1, be1, m1, v1, b2, g2, be2, m2, v2, b3, g3, be3, m3, v3,
      wK1, wK2, wK3, sc, sh);
  hist_kernel<<<AANG, 256, 0, stream>>>(seg, offs);
  fill_kernel<<<AANG, 256, 0, stream>>>(seg, offs, lst16);
  zero_border<<<(NB*PADD*PADD + 255)/256, 256, 0, stream>>>((uint4*)accP, (uint4*)y2P, qcnt);
  conv1_kernel<<<dim3(HW/128, NB), 256, 0, stream>>>(x, wK1, sc, sh, fbuf);
  dht_kernel<<<NB*AANG*2, 512, 0, stream>>>(lst16, offs, (const unsigned int*)fbuf,
                                            (unsigned int*)accP, qcnt);
  conv3x3_kernel<1><<<dim3((M2 + 127)/128, NB), 256, 0, stream>>>(
      accP, wK2, sc + 128, sh + 128, y2P);
  conv3x3_kernel<2><<<dim3((M2 + 127)/128, NB), 256, 0, stream>>>(
      y2P, wK3, sc + 256, sh + 256, d_out);
}

// Round 6
// 727.894 us; speedup vs baseline: 1.0865x; 1.0865x over previous
//
#include <hip/hip_runtime.h>
#include <hip/hip_bf16.h>
#include <math.h>

// Problem constants (fixed shapes from setup_inputs)
#define NB 8
#define CI 256
#define CD 128
#define HH 128
#define WW 128
#define HW (HH*WW)          // 16384
#define AANG 180
#define RRHO 180
#define PADD 182            // 180 + 2 (zero pad for 3x3 convs)
#define M2 (AANG*RRHO)      // 32400 output pixels per image for conv2/3

typedef __attribute__((ext_vector_type(8))) short short8;
typedef __attribute__((ext_vector_type(8))) _Float16 half8;
typedef __attribute__((ext_vector_type(2))) _Float16 h2;
typedef __attribute__((ext_vector_type(4))) float floatx4;
typedef __attribute__((ext_vector_type(2))) float floatx2;

static __device__ __forceinline__ void async_cp16(const void* g, void* l) {
  __builtin_amdgcn_global_load_lds((const __attribute__((address_space(1))) unsigned int*)g,
                                   (__attribute__((address_space(3))) unsigned int*)l,
                                   16, 0, 0);
}

static __device__ __forceinline__ unsigned short f2bf(float f) {
  unsigned int u = __builtin_bit_cast(unsigned int, f);
  unsigned int r = (u + 0x7fffu + ((u >> 16) & 1u)) >> 16;
  return (unsigned short)r;
}

static __device__ __forceinline__ unsigned short f2h(float f) {
  return __builtin_bit_cast(unsigned short, (_Float16)f);
}

// Accumulate both f16 halves of u into separate f32 accumulators.
// v_dot2_f32_f16 with basis vectors: 1 VALU op per channel-add, no unpack.
static __device__ __forceinline__ void acc2(float& aL, float& aH, unsigned int u,
                                            h2 eL, h2 eH) {
  h2 hv = __builtin_bit_cast(h2, u);
#if __has_builtin(__builtin_amdgcn_fdot2)
  aL = __builtin_amdgcn_fdot2(hv, eL, aL, false);
  aH = __builtin_amdgcn_fdot2(hv, eH, aH, false);
#else
  aL += (float)hv.x;
  aH += (float)hv.y;
#endif
}

static __device__ __forceinline__ void acc4(float* aL, float* aH, const uint4& v,
                                            h2 eL, h2 eH) {
  acc2(aL[0], aH[0], v.x, eL, eH);
  acc2(aL[1], aH[1], v.y, eL, eH);
  acc2(aL[2], aH[2], v.z, eL, eH);
  acc2(aL[3], aH[3], v.w, eL, eH);
}

// ---------------------------------------------------------------------------
// prep: weight repack + BN scale/shift folding.
// wK1 fp16 [co][ci] (conv1 f16 MFMA).
// wK2/wK3 bf16 repacked STEP-MAJOR for coalesced conv staging:
//   [step = dydx*2 + (ci>>6)][co 0..127][ci&63]  -> each 16 KB tile contiguous.
// ---------------------------------------------------------------------------
__global__ void prep_kernel(const float* __restrict__ w1, const float* __restrict__ w2,
                            const float* __restrict__ w3,
                            const float* b1, const float* g1, const float* be1,
                            const float* m1, const float* v1,
                            const float* b2, const float* g2, const float* be2,
                            const float* m2, const float* v2,
                            const float* b3, const float* g3, const float* be3,
                            const float* m3, const float* v3,
                            unsigned short* __restrict__ wK1, unsigned short* __restrict__ wK2,
                            unsigned short* __restrict__ wK3,
                            float* __restrict__ sc, float* __restrict__ sh) {
  int idx = blockIdx.x * 256 + threadIdx.x;
  if (idx < 32768) {
    wK1[idx] = f2h(w1[idx]);                       // w1 is already [co][ci]
  } else if (idx < 32768 + 147456) {
    int i = idx - 32768;
    int co = i / 1152, k = i % 1152;
    int dydx = k >> 7, ci = k & 127;
    int dst = (((dydx*2 + (ci >> 6)) * 128 + co) * 64) + (ci & 63);
    wK2[dst] = f2bf(w2[(size_t)(co*128 + ci)*9 + dydx]);
  } else if (idx < 32768 + 2*147456) {
    int i = idx - 32768 - 147456;
    int co = i / 1152, k = i % 1152;
    int dydx = k >> 7, ci = k & 127;
    int dst = (((dydx*2 + (ci >> 6)) * 128 + co) * 64) + (ci & 63);
    wK3[dst] = f2bf(w3[(size_t)(co*128 + ci)*9 + dydx]);
  } else if (idx < 32768 + 2*147456 + 384) {
    int j = idx - 32768 - 2*147456;
    int c = j >> 7, co = j & 127;
    const float* b  = c==0?b1 :(c==1?b2 :b3);
    const float* g  = c==0?g1 :(c==1?g2 :g3);
    const float* be = c==0?be1:(c==1?be2:be3);
    const float* m  = c==0?m1 :(c==1?m2 :m3);
    const float* v  = c==0?v1 :(c==1?v2 :v3);
    float s = g[co] * rsqrtf(v[co] + 1e-5f);
    sc[c*128 + co] = s;
    sh[c*128 + co] = (b[co] - m[co]) * s + be[co];
  }
}

// ---------------------------------------------------------------------------
// Merged hist+fill: seg map lives in LDS (16 KB) -- one kernel instead of two
// and no 2.9 MB seg global round-trip. fp64 binning exactly matches numpy
// (round-half-even via rint). irho = 182/179. Each thread then scatters its
// CONTIGUOUS 64-px raster range so every bin's list is a concatenation of
// few raster-sorted runs (address locality for the DHT gather).
// ---------------------------------------------------------------------------
__global__ void histfill_kernel(unsigned int* __restrict__ offs,
                                unsigned short* __restrict__ lst16) {
  int a = blockIdx.x, t = threadIdx.x;
  __shared__ unsigned char segL[HW];    // 16 KB
  __shared__ unsigned int h[RRHO];
  __shared__ unsigned int pos[RRHO];
  if (t < RRHO) h[t] = 0;
  __syncthreads();
  double th = (double)a * (M_PI / 180.0);
  double Cc = cos(th) / (182.0 / 179.0);
  double Ss = sin(th) / (182.0 / 179.0);
  for (int p = t; p < HW; p += 256) {
    int x = (p & 127) - 64;   // width index
    int y = (p >> 7) - 64;    // height index
    int r = (int)rint(Cc * (double)x + Ss * (double)y) + 90;
    r = r < 0 ? 0 : (r > 179 ? 179 : r);
    segL[p] = (unsigned char)r;
    atomicAdd(&h[r], 1u);
  }
  __syncthreads();
  if (t == 0) {
    unsigned int run = 0;
    for (int r = 0; r < RRHO; ++r) {
      pos[r] = run;
      offs[a*192 + r] = run;
      run += h[r];
    }
    offs[a*192 + RRHO] = run;
  }
  __syncthreads();
  int p0 = t * 64;
  for (int i = 0; i < 64; ++i) {
    int p = p0 + i;
    int r = segL[p];
    unsigned int ix = atomicAdd(&pos[r], 1u);
    lst16[(size_t)a*HW + ix] = (unsigned short)p;
  }
}

// Zero the 1-px borders of the two padded activation buffers (ws is poisoned),
// plus the 8 DHT work-queue counters.
__global__ void zero_border(uint4* __restrict__ accP, uint4* __restrict__ y2P,
                            unsigned int* __restrict__ qcnt) {
  int idx = blockIdx.x * 256 + threadIdx.x;
  if (idx < 8) qcnt[idx] = 0;
  if (idx >= NB * PADD * PADD) return;
  int rc = idx % (PADD * PADD);
  int row = rc / PADD, col = rc % PADD;
  if (row != 0 && row != PADD-1 && col != 0 && col != PADD-1) return;
  uint4 z = {0u, 0u, 0u, 0u};
  size_t base = (size_t)idx * 16;  // 128 bf16 = 16 uint4 per cell
  #pragma unroll
  for (int i = 0; i < 16; ++i) { accP[base + i] = z; y2P[base + i] = z; }
}

// ---------------------------------------------------------------------------
// conv1: 1x1 conv as MFMA GEMM (f16). A = x (fp32 -> f16 via cvt_pkrtz in
// staging), B = wK1 f16 (global_load_lds). Output f[n][pixel][co] f16
// channels-last.
// ---------------------------------------------------------------------------
__global__ __launch_bounds__(256) void conv1_kernel(
    const float* __restrict__ x, const unsigned short* __restrict__ wK,
    const float* __restrict__ sc, const float* __restrict__ sh,
    unsigned short* __restrict__ f) {
  __shared__ short Al[4*128*8];
  __shared__ short Bl[4*128*8];
  int t = threadIdx.x;
  int m0 = blockIdx.x * 128;
  int n = blockIdx.y;
  int lane = t & 63, wv = t >> 6, wm = wv & 1, wn = wv >> 1;
  int mloc = t & 127, octb = t >> 7;
  floatx4 acc[4][4];
  #pragma unroll
  for (int i = 0; i < 4; ++i)
    #pragma unroll
    for (int j = 0; j < 4; ++j) acc[i][j] = (floatx4){0.f, 0.f, 0.f, 0.f};
  const float* xn = x + (size_t)n * CI * HW;
  for (int kc = 0; kc < 8; ++kc) {
    if (kc) __syncthreads();
    // A: load 8 k-strided fp32 per pass, pack to f16 pairs, store [oct][m][8]
    #pragma unroll
    for (int j = 0; j < 2; ++j) {
      int oct = octb + 2*j;
      const float* src = xn + (size_t)(kc*32 + oct*8) * HW + m0 + mloc;
      float v[8];
      #pragma unroll
      for (int e = 0; e < 8; ++e) v[e] = src[(size_t)e * HW];
      uint4 pk;
      pk.x = __builtin_bit_cast(unsigned int, __builtin_amdgcn_cvt_pkrtz(v[0], v[1]));
      pk.y = __builtin_bit_cast(unsigned int, __builtin_amdgcn_cvt_pkrtz(v[2], v[3]));
      pk.z = __builtin_bit_cast(unsigned int, __builtin_amdgcn_cvt_pkrtz(v[4], v[5]));
      pk.w = __builtin_bit_cast(unsigned int, __builtin_amdgcn_cvt_pkrtz(v[6], v[7]));
      *reinterpret_cast<uint4*>(&Al[(size_t)(t + 256*j) * 8]) = pk;
    }
    // B: async 16B direct-to-LDS
    #pragma unroll
    for (int j = 0; j < 2; ++j) {
      int oct = octb + 2*j;
      async_cp16(wK + (size_t)mloc * 256 + kc*32 + oct*8,
                 &Bl[(size_t)((t & 0xFFC0) + 256*j) * 8]);
    }
    __syncthreads();
    int q = lane >> 4, l15 = lane & 15;
    short8 af[4], bfr[4];
    #pragma unroll
    for (int i = 0; i < 4; ++i)
      af[i] = *reinterpret_cast<const short8*>(&Al[((q*128) + wm*64 + i*16 + l15) * 8]);
    #pragma unroll
    for (int j = 0; j < 4; ++j)
      bfr[j] = *reinterpret_cast<const short8*>(&Bl[((q*128) + wn*64 + j*16 + l15) * 8]);
    #pragma unroll
    for (int i = 0; i < 4; ++i)
      #pragma unroll
      for (int j = 0; j < 4; ++j)
        acc[i][j] = __builtin_amdgcn_mfma_f32_16x16x32_f16(
            __builtin_bit_cast(half8, af[i]), __builtin_bit_cast(half8, bfr[j]),
            acc[i][j], 0, 0, 0);
  }
  int q = lane >> 4, l15 = lane & 15;
  #pragma unroll
  for (int j = 0; j < 4; ++j) {
    int co = wn*64 + j*16 + l15;
    float s = sc[co], hb = sh[co];
    #pragma unroll
    for (int i = 0; i < 4; ++i) {
      #pragma unroll
      for (int rg = 0; rg < 4; ++rg) {
        int m = m0 + wm*64 + i*16 + q*4 + rg;
        float v = acc[i][j][rg] * s + hb;
        v = fmaxf(v, 0.f);
        f[((size_t)n * HW + m) * 128 + co] = f2h(v);
      }
    }
  }
}

// ---------------------------------------------------------------------------
// DHT gather v8 (kept from round 5: equal to v6, no spill, FETCH ~67 MB).
// Front/back dual-stream within each bin, 8 dwordx4 in flight, one acc set.
// 512 thr / 8 waves / 33.5 KB LDS -> 4 blocks x 8 waves = 32 waves/CU.
// Per-XCD work queues via HW_REG_XCC_ID keep each image-half in its L2.
// Parked: 3 rounds of MLP attacks moved it 354->277 us; now at a mixed
// VALU/L1-issue equilibrium ~1.65x the pure-L2-BW floor.
// ---------------------------------------------------------------------------
__global__ __launch_bounds__(512, 8) void dht_kernel(
    const unsigned short* __restrict__ lst16, const unsigned int* __restrict__ offs,
    const unsigned int* __restrict__ f, unsigned int* __restrict__ accP,
    unsigned int* __restrict__ qcnt) {
  __shared__ unsigned short Ls[HW];     // 32 KB pixel list for this angle
  __shared__ unsigned int Os[RRHO + 1];
  __shared__ int sWork;
  int t = threadIdx.x;
  if (t == 0) {
    unsigned int xcd;
    asm volatile("s_getreg_b32 %0, hwreg(HW_REG_XCC_ID, 0, 32)" : "=s"(xcd));
    xcd &= 7u;
    int work = 0;
    for (int k = 0; k < 8; ++k) {
      unsigned int q = (xcd + (unsigned int)k) & 7u;
      unsigned int tk = atomicAdd(&qcnt[q], 1u);
      if (tk < 360u) { work = (int)(q * 360u + tk); break; }
    }
    sWork = work;
  }
  __syncthreads();
  int work = sWork;
  int n = work / 360;          // image == (ideally) this XCD
  int rem = work % 360;
  int h = rem / 180;           // channel half; co-resident tickets share h
  int a = rem % 180;
  // Stage list + offsets into LDS (sequential uint4 reads, fully coalesced).
  {
    const uint4* src = (const uint4*)(lst16 + (size_t)a * HW);  // 2048 uint4
    uint4* dst = (uint4*)Ls;
    if (t < RRHO + 1) Os[t] = offs[a*192 + t];
    #pragma unroll
    for (int i = 0; i < 4; ++i) dst[t + 512*i] = src[t + 512*i];
  }
  __syncthreads();
  int w = t >> 6, lane = t & 63;
  int sub = lane >> 3;         // which of 8 pixels in the load group
  int co  = lane & 7;          // channel octet within the half
  // Wave-uniform byte base; per-lane 32-bit offset -> saddr-form dwordx4.
  const char* fb = (const char*)(f + (size_t)n * HW * 64);
  unsigned int loff = (unsigned int)(h*32 + co*4) * 4u;
  const h2 eL = {(_Float16)1.0f, (_Float16)0.0f};
  const h2 eH = {(_Float16)0.0f, (_Float16)1.0f};
  for (int r = w; r < RRHO; r += 8) {
    int lo = (int)Os[r];
    int hi = (int)Os[r+1];
    float accL[4], accH[4];
    #pragma unroll
    for (int j = 0; j < 4; ++j) { accL[j] = 0.f; accH[j] = 0.f; }
    // Dual-stream main loop: 8 loads in flight, one accumulator set.
    while (hi - lo >= 64) {
      unsigned int p0 = Ls[lo + sub];
      unsigned int p1 = Ls[lo + 8 + sub];
      unsigned int p2 = Ls[lo + 16 + sub];
      unsigned int p3 = Ls[lo + 24 + sub];
      unsigned int p4 = Ls[hi - 32 + sub];
      unsigned int p5 = Ls[hi - 24 + sub];
      unsigned int p6 = Ls[hi - 16 + sub];
      unsigned int p7 = Ls[hi - 8 + sub];
      uint4 v0 = *(const uint4*)(fb + ((p0 << 8) + loff));
      uint4 v1 = *(const uint4*)(fb + ((p1 << 8) + loff));
      uint4 v2 = *(const uint4*)(fb + ((p2 << 8) + loff));
      uint4 v3 = *(const uint4*)(fb + ((p3 << 8) + loff));
      uint4 v4 = *(const uint4*)(fb + ((p4 << 8) + loff));
      uint4 v5 = *(const uint4*)(fb + ((p5 << 8) + loff));
      uint4 v6 = *(const uint4*)(fb + ((p6 << 8) + loff));
      uint4 v7 = *(const uint4*)(fb + ((p7 << 8) + loff));
      acc4(accL, accH, v0, eL, eH); acc4(accL, accH, v1, eL, eH);
      acc4(accL, accH, v2, eL, eH); acc4(accL, accH, v3, eL, eH);
      acc4(accL, accH, v4, eL, eH); acc4(accL, accH, v5, eL, eH);
      acc4(accL, accH, v6, eL, eH); acc4(accL, accH, v7, eL, eH);
      lo += 32; hi -= 32;
    }
    // Remaining [lo, hi): fewer than 64 pixels.
    for (; lo + 32 <= hi; lo += 32) {
      unsigned int p0 = Ls[lo + sub];
      unsigned int p1 = Ls[lo + 8 + sub];
      unsigned int p2 = Ls[lo + 16 + sub];
      unsigned int p3 = Ls[lo + 24 + sub];
      uint4 v0 = *(const uint4*)(fb + ((p0 << 8) + loff));
      uint4 v1 = *(const uint4*)(fb + ((p1 << 8) + loff));
      uint4 v2 = *(const uint4*)(fb + ((p2 << 8) + loff));
      uint4 v3 = *(const uint4*)(fb + ((p3 << 8) + loff));
      acc4(accL, accH, v0, eL, eH); acc4(accL, accH, v1, eL, eH);
      acc4(accL, accH, v2, eL, eH); acc4(accL, accH, v3, eL, eH);
    }
    for (; lo + 8 <= hi; lo += 8) {
      unsigned int p0 = Ls[lo + sub];
      uint4 v0 = *(const uint4*)(fb + ((p0 << 8) + loff));
      acc4(accL, accH, v0, eL, eH);
    }
    if (lo < hi) {
      int idx = lo + sub;
      int cl = idx < hi ? idx : (hi - 1);
      unsigned int p0 = Ls[cl];
      uint4 v0 = *(const uint4*)(fb + ((p0 << 8) + loff));
      if (idx >= hi) { v0.x = 0; v0.y = 0; v0.z = 0; v0.w = 0; }
      acc4(accL, accH, v0, eL, eH);
    }
    // Butterfly reduce across the 8 pixel-subgroups (lane bits 3,4,5).
    #pragma unroll
    for (int m = 8; m <= 32; m <<= 1) {
      #pragma unroll
      for (int j = 0; j < 4; ++j) {
        accL[j] += __shfl_xor(accL[j], m, 64);
        accH[j] += __shfl_xor(accH[j], m, 64);
      }
    }
    if (sub == 0) {
      uint4 out;
      out.x = (unsigned int)f2bf(accL[0]) | ((unsigned int)f2bf(accH[0]) << 16);
      out.y = (unsigned int)f2bf(accL[1]) | ((unsigned int)f2bf(accH[1]) << 16);
      out.z = (unsigned int)f2bf(accL[2]) | ((unsigned int)f2bf(accH[2]) << 16);
      out.w = (unsigned int)f2bf(accL[3]) | ((unsigned int)f2bf(accH[3]) << 16);
      size_t o = (((size_t)n*PADD + (a+1))*PADD + (r+1))*64 + h*32 + co*4;
      *(uint4*)(accP + o) = out;
    }
  }
}

// ---------------------------------------------------------------------------
// 3x3 conv (round-4 single-buffer structure, the measured best) + pinned
// occupancy: __launch_bounds__(256, 4) caps VGPR at 128 so 4 blocks/CU
// co-reside (32 KB LDS allows 5). Inter-block wave overlap hides the
// stage->barrier drain -- the mechanism the explicit 64 KB double-buffer
// (round 5) destroyed by halving occupancy (regressed +40 us; reverted).
// BK=64 (step = dydx*2 + ci-half, 18 steps), LDS tiles [128 rows][64 chans],
// line-coalesced staging (8 rows x 128 B per wave-op; step-major weights),
// mod-8 octet rotation swizzle on both sides.
// MODE 1: conv2 -> bf16 padded channels-last out. MODE 2: conv3 -> fp32 NCHW,
// operands swapped so stores are contiguous along rho.
// ---------------------------------------------------------------------------
template<int MODE>
__global__ __launch_bounds__(256, 4) void conv3x3_kernel(
    const unsigned short* __restrict__ inP,   // [N][182][182][128] bf16
    const unsigned short* __restrict__ wKr,   // [18][128][64] bf16 step-major
    const float* __restrict__ sc, const float* __restrict__ sh,
    void* __restrict__ outp) {
  __shared__ short Al[128*64];   // 16 KB
  __shared__ short Bl[128*64];   // 16 KB
  int t = threadIdx.x;
  int m0 = blockIdx.x * 128;
  int n = blockIdx.y;
  int lane = t & 63, w = t >> 6, wm = w & 1, wn = w >> 1;
  floatx4 acc[4][4];
  #pragma unroll
  for (int i = 0; i < 4; ++i)
    #pragma unroll
    for (int j = 0; j < 4; ++j) acc[i][j] = (floatx4){0.f, 0.f, 0.f, 0.f};

  // Staging geometry: 1024 slots of 16 B; slot s = (w*4+i)*64 + lane;
  // row = s>>3, oct slot p = s&7. Source octet = (p - row) & 7 == the
  // per-thread constant below (same for all i).
  int srcOct = ((lane & 7) - (lane >> 3)) & 7;
  const unsigned short* rpA[4];
  unsigned int offB[4];
  #pragma unroll
  for (int i = 0; i < 4; ++i) {
    int row = w*32 + i*8 + (lane >> 3);
    int mg = m0 + row; if (mg > M2 - 1) mg = M2 - 1;
    int oa = mg / 180, orr = mg % 180;
    rpA[i] = inP + (((size_t)n*PADD + oa)*PADD + orr)*128 + srcOct*8;
    offB[i] = (unsigned int)(row*64 + srcOct*8);
  }

  for (int step = 0; step < 18; ++step) {
    int dydx = step >> 1, cc2 = step & 1;
    int dy = (dydx * 11) >> 5, dx = dydx - dy*3;
    int doff = (dy*PADD + dx)*128 + cc2*64;
    if (step) __syncthreads();
    #pragma unroll
    for (int i = 0; i < 4; ++i) {
      async_cp16(rpA[i] + doff, &Al[(size_t)((w*4 + i)*64 + lane) * 8]);
      async_cp16(wKr + (size_t)step*8192 + offB[i],
                 &Bl[(size_t)((w*4 + i)*64 + lane) * 8]);
    }
    __syncthreads();
    int q = lane >> 4, l15 = lane & 15;
    #pragma unroll
    for (int kk = 0; kk < 2; ++kk) {
      int o = kk*4 + q;
      int swz = ((o + l15) & 7) * 8;
      short8 rf[4], cf[4];
      #pragma unroll
      for (int i = 0; i < 4; ++i) {
        int addr = (wm*64 + i*16 + l15)*64 + swz;
        rf[i] = *reinterpret_cast<const short8*>(MODE == 1 ? &Al[addr] : &Bl[addr]);
      }
      #pragma unroll
      for (int j = 0; j < 4; ++j) {
        int addr = (wn*64 + j*16 + l15)*64 + swz;
        cf[j] = *reinterpret_cast<const short8*>(MODE == 1 ? &Bl[addr] : &Al[addr]);
      }
      #pragma unroll
      for (int i = 0; i < 4; ++i)
        #pragma unroll
        for (int j = 0; j < 4; ++j)
          acc[i][j] = __builtin_amdgcn_mfma_f32_16x16x32_bf16(rf[i], cf[j], acc[i][j], 0, 0, 0);
    }
  }
  int q = lane >> 4, l15 = lane & 15;
  if (MODE == 1) {
    unsigned short* out = (unsigned short*)outp;
    #pragma unroll
    for (int j = 0; j < 4; ++j) {
      int co = wn*64 + j*16 + l15;
      float s = sc[co], hb = sh[co];
      #pragma unroll
      for (int i = 0; i < 4; ++i) {
        #pragma unroll
        for (int rg = 0; rg < 4; ++rg) {
          int m = m0 + wm*64 + i*16 + q*4 + rg;
          if (m < M2) {
            float v = fmaxf(acc[i][j][rg] * s + hb, 0.f);
            int oa2 = m / 180, or2 = m % 180;
            out[(((size_t)n*PADD + oa2 + 1)*PADD + or2 + 1)*128 + co] = f2bf(v);
          }
        }
      }
    }
  } else {
    float* out = (float*)outp;
    #pragma unroll
    for (int i = 0; i < 4; ++i) {
      #pragma unroll
      for (int rg = 0; rg < 4; ++rg) {
        int co = wm*64 + i*16 + q*4 + rg;
        float s = sc[co], hb = sh[co];
        #pragma unroll
        for (int j = 0; j < 4; ++j) {
          int m = m0 + wn*64 + j*16 + l15;
          if (m < M2) {
            float v = fmaxf(acc[i][j][rg] * s + hb, 0.f);
            out[((size_t)n*128 + co)*M2 + m] = v;
          }
        }
      }
    }
  }
}

// ---------------------------------------------------------------------------
extern "C" void kernel_launch(void* const* d_in, const int* in_sizes, int n_in,
                              void* d_out, int out_size, void* d_ws, size_t ws_size,
                              hipStream_t stream) {
  const float* x  = (const float*)d_in[0];
  const float* w1 = (const float*)d_in[1];
  const float* b1 = (const float*)d_in[2];
  const float* g1 = (const float*)d_in[3];
  const float* be1= (const float*)d_in[4];
  const float* m1 = (const float*)d_in[5];
  const float* v1 = (const float*)d_in[6];
  const float* w2 = (const float*)d_in[7];
  const float* b2 = (const float*)d_in[8];
  const float* g2 = (const float*)d_in[9];
  const float* be2= (const float*)d_in[10];
  const float* m2 = (const float*)d_in[11];
  const float* v2 = (const float*)d_in[12];
  const float* w3 = (const float*)d_in[13];
  const float* b3 = (const float*)d_in[14];
  const float* g3 = (const float*)d_in[15];
  const float* be3= (const float*)d_in[16];
  const float* m3 = (const float*)d_in[17];
  const float* v3 = (const float*)d_in[18];

  size_t off = 0;
  char* ws = (char*)d_ws;
  auto alloc = [&](size_t sz) -> void* {
    void* p = ws + off;
    off = (off + sz + 255) & ~(size_t)255;
    return p;
  };
  unsigned short* fbuf = (unsigned short*)alloc((size_t)NB*HW*128*2);        // 33.6 MB
  unsigned short* accP = (unsigned short*)alloc((size_t)NB*PADD*PADD*128*2); // 67.8 MB
  unsigned short* y2P  = (unsigned short*)alloc((size_t)NB*PADD*PADD*128*2); // 67.8 MB
  unsigned short* wK1  = (unsigned short*)alloc(32768*2);
  unsigned short* wK2  = (unsigned short*)alloc(147456*2);
  unsigned short* wK3  = (unsigned short*)alloc(147456*2);
  float* sc = (float*)alloc(384*4);
  float* sh = (float*)alloc(384*4);
  unsigned int* offs  = (unsigned int*)alloc((size_t)AANG*192*4);
  unsigned short* lst16 = (unsigned short*)alloc((size_t)AANG*HW*2);
  unsigned int* qcnt  = (unsigned int*)alloc(8*4);

  prep_kernel<<<1282, 256, 0, stream>>>(w1, w2, w3,
      b1, g1, be1, m1, v1, b2, g2, be2, m2, v2, b3, g3, be3, m3, v3,
      wK1, wK2, wK3, sc, sh);
  histfill_kernel<<<AANG, 256, 0, stream>>>(offs, lst16);
  zero_border<<<(NB*PADD*PADD + 255)/256, 256, 0, stream>>>((uint4*)accP, (uint4*)y2P, qcnt);
  conv1_kernel<<<dim3(HW/128, NB), 256, 0, stream>>>(x, wK1, sc, sh, fbuf);
  dht_kernel<<<NB*AANG*2, 512, 0, stream>>>(lst16, offs, (const unsigned int*)fbuf,
                                            (unsigned int*)accP, qcnt);
  conv3x3_kernel<1><<<dim3((M2 + 127)/128, NB), 256, 0, stream>>>(
      accP, wK2, sc + 128, sh + 128, y2P);
  conv3x3_kernel<2><<<dim3((M2 + 127)/128, NB), 256, 0, stream>>>(
      y2P, wK3, sc + 256, sh + 256, d_out);
}